// Round 1
// baseline (492.969 us; speedup 1.0000x reference)
//
#include <hip/hip_runtime.h>
#include <hip/hip_bf16.h>

#define NROW 384
#define GD   1935
#define DD   300      // D1 = D2 = OUT
#define KP   320      // padded o (K of big gemm)
#define DP   304      // padded p

// workspace offsets (floats)
#define OFF_SIG1 0
#define OFF_SIG2 2048
#define OFF_W    4096
#define OFF_F1   4608      // 384*300
#define OFF_F2   119808
#define OFF_A    235008    // 384*320 each
#define OFF_B    357888
#define OFF_C    480768
#define OFF_D    603648
#define OFF_FC3  726528    // bf16 area: 304*320 ushorts (=48640 floats)

typedef short short8 __attribute__((ext_vector_type(8)));
typedef float floatx4 __attribute__((ext_vector_type(4)));

__device__ inline unsigned short f2bf(float x){
  union { float f; unsigned u; } v; v.f = x;
  unsigned r = v.u + 0x7fffu + ((v.u >> 16) & 1u);
  return (unsigned short)(r >> 16);
}

// sigmoid(gate1/2), softmax(weight_loc)
__global__ void k_prep(const float* g1, const float* g2, const float* wloc, float* ws){
  int t = blockIdx.x * 256 + threadIdx.x;
  if (t < GD) ws[OFF_SIG1 + t] = 1.f / (1.f + expf(-g1[t]));
  else if (t < 2*GD) ws[OFF_SIG2 + t - GD] = 1.f / (1.f + expf(-g2[t - GD]));
  else if (t == 2*GD){
    float a = wloc[0], b = wloc[1];
    float m = fmaxf(a, b);
    float ea = expf(a - m), eb = expf(b - m);
    ws[OFF_W + 0] = ea / (ea + eb);
    ws[OFF_W + 1] = eb / (ea + eb);
  }
}

// fc3_w (300x300) -> bf16 padded [304][320]
__global__ void k_cvt(const float* fc3, float* ws){
  int t = blockIdx.x * 256 + threadIdx.x;   // 304*320 = 97280 = 380*256
  int p = t / KP, k = t % KP;
  float v = (p < DD && k < DD) ? fc3[p * DD + k] : 0.f;
  ((unsigned short*)(ws + OFF_FC3))[t] = f2bf(v);
}

// f{1,2}[384][300] = (feature ∘ sigmoid(gate)) @ E(1935x300)
__global__ __launch_bounds__(256) void k_gemm_gated(const float* x1, const float* x2,
                                                    const float* E, float* ws){
  int z = blockIdx.z;
  const float* X   = z ? x2 : x1;
  const float* sig = ws + (z ? OFF_SIG2 : OFF_SIG1);
  float* out       = ws + (z ? OFF_F2 : OFF_F1);
  int n0 = blockIdx.x * 32, c0 = blockIdx.y * 32;
  __shared__ float As[32][34];  // [k][n]
  __shared__ float Bs[32][34];  // [k][c]
  int t = threadIdx.x;
  int tr = t >> 3, tq = t & 7;
  int ty = t >> 4, tx = t & 15;
  float a00 = 0, a01 = 0, a10 = 0, a11 = 0;
  for (int k0 = 0; k0 < GD; k0 += 32){
    #pragma unroll
    for (int i = 0; i < 4; ++i){
      int kk = tq * 4 + i, k = k0 + kk;
      float v = 0.f;
      if (k < GD) v = X[(n0 + tr) * GD + k] * sig[k];
      As[kk][tr] = v;
    }
    #pragma unroll
    for (int i = 0; i < 4; ++i){
      int cc = tq * 4 + i, c = c0 + cc, k = k0 + tr;
      float v = 0.f;
      if (k < GD && c < DD) v = E[k * DD + c];
      Bs[tr][cc] = v;
    }
    __syncthreads();
    #pragma unroll
    for (int kk = 0; kk < 32; ++kk){
      float a0 = As[kk][ty*2], a1 = As[kk][ty*2+1];
      float b0 = Bs[kk][tx*2], b1 = Bs[kk][tx*2+1];
      a00 += a0*b0; a01 += a0*b1; a10 += a1*b0; a11 += a1*b1;
    }
    __syncthreads();
  }
  int na = n0 + ty*2, ca = c0 + tx*2;
  if (ca     < DD){ out[na*DD + ca]       = a00; out[(na+1)*DD + ca]     = a10; }
  if (ca + 1 < DD){ out[na*DD + ca + 1]   = a01; out[(na+1)*DD + ca + 1] = a11; }
}

// Ahat[n][o]=w0*(f1·Wa[o,:]+b1[o]) (z=0) ; Bhat[m][o]=w0*(f2·Wb[o,:]) (z=1); o>=300 -> 0
__global__ __launch_bounds__(256) void k_sem(const float* fc1w, const float* fc1b, float* ws){
  int z = blockIdx.z;
  const float* X = ws + (z ? OFF_F2 : OFF_F1);
  float* out     = ws + (z ? OFF_B : OFF_A);
  int doff = z ? DD : 0;
  float w0 = ws[OFF_W];
  int r0 = blockIdx.x * 32, o0 = blockIdx.y * 32;
  __shared__ float As[32][34];  // [d][r]
  __shared__ float Bs[32][34];  // [d][o]
  int t = threadIdx.x;
  int tr = t >> 3, tq = t & 7;
  int ty = t >> 4, tx = t & 15;
  float a00 = 0, a01 = 0, a10 = 0, a11 = 0;
  for (int d0 = 0; d0 < DD; d0 += 32){
    #pragma unroll
    for (int i = 0; i < 4; ++i){
      int dd = tq * 4 + i, d = d0 + dd;
      float v = 0.f;
      if (d < DD) v = X[(r0 + tr) * DD + d];
      As[dd][tr] = v;
    }
    #pragma unroll
    for (int i = 0; i < 4; ++i){
      int dd = tq * 4 + i, d = d0 + dd;
      int o = o0 + tr;
      float v = 0.f;
      if (d < DD && o < DD) v = fc1w[o * (2*DD) + doff + d];
      Bs[dd][tr] = v;
    }
    __syncthreads();
    #pragma unroll
    for (int dd = 0; dd < 32; ++dd){
      float a0 = As[dd][ty*2], a1 = As[dd][ty*2+1];
      float b0 = Bs[dd][tx*2], b1 = Bs[dd][tx*2+1];
      a00 += a0*b0; a01 += a0*b1; a10 += a1*b0; a11 += a1*b1;
    }
    __syncthreads();
  }
  int ra = r0 + ty*2, oa = o0 + tx*2;
  #pragma unroll
  for (int i = 0; i < 2; ++i){
    int o = oa + i;
    float bias = (o < DD && z == 0) ? fc1b[o] : 0.f;
    float v0 = (o < DD) ? w0 * ((i ? a01 : a00) + bias) : 0.f;
    float v1 = (o < DD) ? w0 * ((i ? a11 : a10) + bias) : 0.f;
    out[ra * KP + o]       = v0;
    out[(ra + 1) * KP + o] = v1;
  }
}

// Chat[n][o]=w1*(box1·Wa2[o,:]+b2[o]) (z=0); Dhat[m][o]=w1*(box2·Wb2[o,:]) (z=1)
__global__ void k_spa(const float* box1, const float* box2, const float* fc2w,
                      const float* fc2b, float* ws){
  int z = blockIdx.y;
  const float* bx = z ? box2 : box1;
  float* out = ws + (z ? OFF_D : OFF_C);
  int joff = z ? 5 : 0;
  float w1 = ws[OFF_W + 1];
  int t = blockIdx.x * 256 + threadIdx.x;  // 384*320 = 122880 = 480*256
  int r = t / KP, o = t % KP;
  float v = 0.f;
  if (o < DD){
    const float* b = bx + r * 5;
    const float* wr = fc2w + o * 10 + joff;
    v = b[0]*wr[0] + b[1]*wr[1] + b[2]*wr[2] + b[3]*wr[3] + b[4]*wr[4];
    if (!z) v += fc2b[o];
    v *= w1;
  }
  out[t] = v;
}

// out[n][m][p] = sum_o mixed * fc3[p][o] + fc3b[p]; mixed built in LDS, bf16 MFMA
__global__ __launch_bounds__(256) void k_main(const float* fc3b, float* out, const float* ws){
  __shared__ __align__(16) unsigned short smix[64][40];
  __shared__ __align__(16) unsigned short swt[DP][40];
  const unsigned short* fc3bf = (const unsigned short*)(ws + OFF_FC3);
  int t = threadIdx.x;
  int mt0 = blockIdx.x * 64;
  int n = blockIdx.y;
  const float* Ah = ws + OFF_A + n * KP;
  const float* Ch = ws + OFF_C + n * KP;
  const float* Bh = ws + OFF_B;
  const float* Dh = ws + OFF_D;
  int lane = t & 63, wave = t >> 6;
  int col = lane & 15, quad = lane >> 4;
  floatx4 acc[19];
  #pragma unroll
  for (int i = 0; i < 19; ++i) acc[i] = (floatx4){0.f, 0.f, 0.f, 0.f};

  int ml = t >> 2, j = t & 3;
  int mg = mt0 + ml;
  for (int kc = 0; kc < 10; ++kc){
    int k0 = kc * 32;
    {   // build mixed tile [64 m][32 k] in bf16
      int kb = k0 + j * 8;
      const float4* pa = (const float4*)(Ah + kb);
      const float4* pc = (const float4*)(Ch + kb);
      const float4* pb = (const float4*)(Bh + (size_t)mg * KP + kb);
      const float4* pd = (const float4*)(Dh + (size_t)mg * KP + kb);
      float4 a0 = pa[0], a1 = pa[1];
      float4 c0 = pc[0], c1 = pc[1];
      float4 b0 = pb[0], b1 = pb[1];
      float4 d0 = pd[0], d1 = pd[1];
      union { unsigned short s[8]; uint4 v; } u;
      u.s[0] = f2bf(fmaxf(a0.x + b0.x, 0.f) + fmaxf(c0.x + d0.x, 0.f));
      u.s[1] = f2bf(fmaxf(a0.y + b0.y, 0.f) + fmaxf(c0.y + d0.y, 0.f));
      u.s[2] = f2bf(fmaxf(a0.z + b0.z, 0.f) + fmaxf(c0.z + d0.z, 0.f));
      u.s[3] = f2bf(fmaxf(a0.w + b0.w, 0.f) + fmaxf(c0.w + d0.w, 0.f));
      u.s[4] = f2bf(fmaxf(a1.x + b1.x, 0.f) + fmaxf(c1.x + d1.x, 0.f));
      u.s[5] = f2bf(fmaxf(a1.y + b1.y, 0.f) + fmaxf(c1.y + d1.y, 0.f));
      u.s[6] = f2bf(fmaxf(a1.z + b1.z, 0.f) + fmaxf(c1.z + d1.z, 0.f));
      u.s[7] = f2bf(fmaxf(a1.w + b1.w, 0.f) + fmaxf(c1.w + d1.w, 0.f));
      *(uint4*)&smix[ml][j * 8] = u.v;
    }
    // stage weight K-slice [304 p][32 k]
    for (int i = t; i < DP * 4; i += 256){
      int p = i >> 2, q = i & 3;
      uint4 w = *(const uint4*)(fc3bf + p * KP + k0 + q * 8);
      *(uint4*)&swt[p][q * 8] = w;
    }
    __syncthreads();
    short8 af = *(const short8*)&smix[wave * 16 + col][quad * 8];
    #pragma unroll
    for (int pt = 0; pt < 19; ++pt){
      short8 bf = *(const short8*)&swt[pt * 16 + col][quad * 8];
      acc[pt] = __builtin_amdgcn_mfma_f32_16x16x32_bf16(af, bf, acc[pt], 0, 0, 0);
    }
    __syncthreads();
  }
  #pragma unroll
  for (int pt = 0; pt < 19; ++pt){
    int p = pt * 16 + col;
    if (p < DD){
      float bias = fc3b[p];
      #pragma unroll
      for (int r = 0; r < 4; ++r){
        int m = mt0 + wave * 16 + quad * 4 + r;
        out[((size_t)n * NROW + m) * DD + p] = acc[pt][r] + bias;
      }
    }
  }
}

extern "C" void kernel_launch(void* const* d_in, const int* in_sizes, int n_in,
                              void* d_out, int out_size, void* d_ws, size_t ws_size,
                              hipStream_t stream) {
  const float* feature1 = (const float*)d_in[0];
  const float* box1     = (const float*)d_in[1];
  const float* feature2 = (const float*)d_in[2];
  const float* box2     = (const float*)d_in[3];
  const float* E        = (const float*)d_in[4];
  const float* gate1    = (const float*)d_in[5];
  const float* gate2    = (const float*)d_in[6];
  const float* wloc     = (const float*)d_in[7];
  const float* fc1w     = (const float*)d_in[8];
  const float* fc1b     = (const float*)d_in[9];
  const float* fc2w     = (const float*)d_in[10];
  const float* fc2b     = (const float*)d_in[11];
  const float* fc3w     = (const float*)d_in[12];
  const float* fc3b     = (const float*)d_in[13];
  float* out = (float*)d_out;
  float* ws  = (float*)d_ws;

  hipLaunchKernelGGL(k_prep, dim3(16), dim3(256), 0, stream, gate1, gate2, wloc, ws);
  hipLaunchKernelGGL(k_cvt, dim3(380), dim3(256), 0, stream, fc3w, ws);
  hipLaunchKernelGGL(k_gemm_gated, dim3(12, 10, 2), dim3(256), 0, stream,
                     feature1, feature2, E, ws);
  hipLaunchKernelGGL(k_sem, dim3(12, 10, 2), dim3(256), 0, stream, fc1w, fc1b, ws);
  hipLaunchKernelGGL(k_spa, dim3(480, 2), dim3(256), 0, stream,
                     box1, box2, fc2w, fc2b, ws);
  hipLaunchKernelGGL(k_main, dim3(6, NROW), dim3(256), 0, stream, fc3b, out, ws);
}

// Round 2
// 334.270 us; speedup vs baseline: 1.4748x; 1.4748x over previous
//
#include <hip/hip_runtime.h>
#include <hip/hip_bf16.h>

#define NROW 384
#define GD   1935
#define GK   1952     // padded gate dim (61*32)
#define DD   300
#define KP   320      // padded o
#define DP   304      // padded p

// workspace offsets (in floats)
#define OFF_SIG1 0
#define OFF_SIG2 2048
#define OFF_W    4096
#define OFF_XBF  4112      // ushort[2][384][1952]  (749568 floats)
#define OFF_EBT  753680    // ushort[320][1952]     (312320 floats)  E transposed
#define OFF_FC1B 1066000   // ushort[2][320][320]   (102400 floats)
#define OFF_FC3B 1168400   // ushort[304][320]      (48640 floats)
#define OFF_F1B  1217040   // ushort[2][384][320]   (122880 floats)
#define OFF_AB   1339920   // float[2][384][320]    Ahat | Bhat
#define OFF_CD   1585680   // float[2][384][320]    Chat | Dhat

typedef short short8 __attribute__((ext_vector_type(8)));
typedef float floatx4 __attribute__((ext_vector_type(4)));

__device__ inline unsigned short f2bf(float x){
  union { float f; unsigned u; } v; v.f = x;
  unsigned r = v.u + 0x7fffu + ((v.u >> 16) & 1u);
  return (unsigned short)(r >> 16);
}

// sigmoid(gate1/2), softmax(weight_loc)
__global__ void k_prep(const float* g1, const float* g2, const float* wloc, float* ws){
  int t = blockIdx.x * 256 + threadIdx.x;
  if (t < GD) ws[OFF_SIG1 + t] = 1.f / (1.f + expf(-g1[t]));
  else if (t < 2*GD) ws[OFF_SIG2 + t - GD] = 1.f / (1.f + expf(-g2[t - GD]));
  else if (t == 2*GD){
    float a = wloc[0], b = wloc[1];
    float m = fmaxf(a, b);
    float ea = expf(a - m), eb = expf(b - m);
    ws[OFF_W + 0] = ea / (ea + eb);
    ws[OFF_W + 1] = eb / (ea + eb);
  }
}

// all bf16 conversions in one pass
// tasks: Xbf[2][384][1952] | EbfT[320][1952] | fc1bf[2][320][320] | fc3bf[304][320]
#define NX  (2*384*GK)
#define NE  (KP*GK)
#define NF1 (2*KP*KP)
#define NF3 (DP*KP)
__global__ void k_cvt_all(const float* f1, const float* f2, const float* E,
                          const float* fc1w, const float* fc3w, float* ws){
  int t = blockIdx.x * 256 + threadIdx.x;
  unsigned short* xbf  = (unsigned short*)(ws + OFF_XBF);
  unsigned short* ebt  = (unsigned short*)(ws + OFF_EBT);
  unsigned short* f1b  = (unsigned short*)(ws + OFF_FC1B);
  unsigned short* f3b  = (unsigned short*)(ws + OFF_FC3B);
  if (t < NX){
    int z = t / (384*GK); int r = t - z*384*GK;
    int n = r / GK, k = r - n*GK;
    const float* X   = z ? f2 : f1;
    const float* sig = ws + (z ? OFF_SIG2 : OFF_SIG1);
    float v = (k < GD) ? X[n*GD + k] * sig[k] : 0.f;
    xbf[t] = f2bf(v);
  } else if (t < NX + NE){
    int r = t - NX;
    int c = r / GK, k = r - c*GK;
    float v = (k < GD && c < DD) ? E[k*DD + c] : 0.f;
    ebt[r] = f2bf(v);
  } else if (t < NX + NE + NF1){
    int r = t - NX - NE;
    int z = r / (KP*KP); int r2 = r - z*KP*KP;
    int o = r2 / KP, d = r2 - o*KP;
    float v = (o < DD && d < DD) ? fc1w[o*(2*DD) + z*DD + d] : 0.f;
    f1b[r] = f2bf(v);
  } else {
    int r = t - NX - NE - NF1;
    int p = r / KP, k = r - p*KP;
    float v = (p < DD && k < DD) ? fc3w[p*DD + k] : 0.f;
    f3b[r] = f2bf(v);
  }
}

// gated GEMM: f1bf[z][384][320] = Xbf[z][384][1952] @ EbfT[320][1952]^T (bf16 out)
// one 16x16 tile per wave; 480 tiles per z; grid (120, 2) x 256
__global__ __launch_bounds__(256) void k_gg(float* ws){
  int z = blockIdx.y;
  const unsigned short* X   = (const unsigned short*)(ws + OFF_XBF) + z*384*GK;
  const unsigned short* Ebt = (const unsigned short*)(ws + OFF_EBT);
  unsigned short* out       = (unsigned short*)(ws + OFF_F1B) + z*384*KP;
  int t = threadIdx.x, lane = t & 63;
  int id = blockIdx.x * 4 + (t >> 6);      // 0..479
  int mt = id / 20, ct = id - mt*20;
  int col = lane & 15, quad = lane >> 4;
  const unsigned short* ap = X   + (mt*16 + col)*GK + quad*8;
  const unsigned short* bp = Ebt + (ct*16 + col)*GK + quad*8;
  floatx4 acc = (floatx4){0.f,0.f,0.f,0.f};
  for (int kc = 0; kc < 61; ++kc){
    short8 a = *(const short8*)(ap + kc*32);
    short8 b = *(const short8*)(bp + kc*32);
    acc = __builtin_amdgcn_mfma_f32_16x16x32_bf16(a, b, acc, 0, 0, 0);
  }
  int c = ct*16 + col;
  #pragma unroll
  for (int r = 0; r < 4; ++r){
    int m = mt*16 + quad*4 + r;
    out[m*KP + c] = (c < DD) ? f2bf(acc[r]) : (unsigned short)0;
  }
}

// semantic: AB[z][384][320] = w0*(f1bf[z] @ fc1bf[z]^T (+b1 if z==0)); o>=300 -> 0
__global__ __launch_bounds__(256) void k_sem(const float* fc1b, float* ws){
  int z = blockIdx.y;
  const unsigned short* F = (const unsigned short*)(ws + OFF_F1B) + z*384*KP;
  const unsigned short* W = (const unsigned short*)(ws + OFF_FC1B) + z*KP*KP;
  float* out = ws + OFF_AB + z*384*KP;
  float w0 = ws[OFF_W];
  int t = threadIdx.x, lane = t & 63;
  int id = blockIdx.x * 4 + (t >> 6);      // 0..479
  int rt = id / 20, ot = id - rt*20;
  int col = lane & 15, quad = lane >> 4;
  const unsigned short* ap = F + (rt*16 + col)*KP + quad*8;
  const unsigned short* bp = W + (ot*16 + col)*KP + quad*8;
  floatx4 acc = (floatx4){0.f,0.f,0.f,0.f};
  #pragma unroll
  for (int kc = 0; kc < 10; ++kc){
    short8 a = *(const short8*)(ap + kc*32);
    short8 b = *(const short8*)(bp + kc*32);
    acc = __builtin_amdgcn_mfma_f32_16x16x32_bf16(a, b, acc, 0, 0, 0);
  }
  int o = ot*16 + col;
  float bias = (z == 0 && o < DD) ? fc1b[o] : 0.f;
  #pragma unroll
  for (int r = 0; r < 4; ++r){
    int rr = rt*16 + quad*4 + r;
    out[rr*KP + o] = (o < DD) ? w0 * (acc[r] + bias) : 0.f;
  }
}

// spatial: CD[z][384][320] = w1*(box @ fc2 half (+b2 if z==0)); o>=300 -> 0
__global__ void k_spa(const float* box1, const float* box2, const float* fc2w,
                      const float* fc2b, float* ws){
  int z = blockIdx.y;
  const float* bx = z ? box2 : box1;
  float* out = ws + OFF_CD + z*384*KP;
  int joff = z ? 5 : 0;
  float w1 = ws[OFF_W + 1];
  int t = blockIdx.x * 256 + threadIdx.x;  // 384*320 = 122880 = 480*256
  int r = t / KP, o = t - r*KP;
  float v = 0.f;
  if (o < DD){
    const float* b = bx + r * 5;
    const float* wr = fc2w + o * 10 + joff;
    v = b[0]*wr[0] + b[1]*wr[1] + b[2]*wr[2] + b[3]*wr[3] + b[4]*wr[4];
    if (!z) v += fc2b[o];
    v *= w1;
  }
  out[t] = v;
}

// main: out[n][m][p] = sum_o mixed(n,m,o)*fc3[p][o] + fc3b[p]
// block: 128 m x 304 p for one n; 512 thr (8 waves); LDS in MFMA frag order
__global__ __launch_bounds__(512, 4) void k_main(const float* fc3b, float* out, const float* ws){
  __shared__ __align__(16) unsigned short smix[512 * 8];    // slot t: 16B A-frag
  __shared__ __align__(16) unsigned short swt[1216 * 8];    // slot pt*64+lane
  const unsigned short* fc3bf = (const unsigned short*)(ws + OFF_FC3B);
  int t = threadIdx.x;
  int lane = t & 63, wave = t >> 6;
  int col = lane & 15, quad = lane >> 4;
  int mt0 = blockIdx.x * 128;
  int n = blockIdx.y;
  const float* Ah = ws + OFF_AB + n * KP;
  const float* Bh = ws + OFF_AB + 384 * KP;
  const float* Ch = ws + OFF_CD + n * KP;
  const float* Dh = ws + OFF_CD + 384 * KP;

  floatx4 acc[19];
  #pragma unroll
  for (int i = 0; i < 19; ++i) acc[i] = (floatx4){0.f,0.f,0.f,0.f};

  // builder decomposition: slot t = w_b*64 + j*16 + colb
  int w_b  = t >> 6;
  int j    = (t >> 4) & 3;
  int colb = t & 15;
  int mg = mt0 + w_b*16 + colb;
  const float* pB = Bh + (size_t)mg * KP;
  const float* pD = Dh + (size_t)mg * KP;

  for (int kc = 0; kc < 10; ++kc){
    int kb = kc*32 + j*8;
    {
      union { unsigned short s[8]; uint4 v; } u;
      float4 a0 = *(const float4*)(Ah + kb);
      float4 c0 = *(const float4*)(Ch + kb);
      float4 b0 = *(const float4*)(pB + kb);
      float4 d0 = *(const float4*)(pD + kb);
      u.s[0] = f2bf(fmaxf(a0.x + b0.x, 0.f) + fmaxf(c0.x + d0.x, 0.f));
      u.s[1] = f2bf(fmaxf(a0.y + b0.y, 0.f) + fmaxf(c0.y + d0.y, 0.f));
      u.s[2] = f2bf(fmaxf(a0.z + b0.z, 0.f) + fmaxf(c0.z + d0.z, 0.f));
      u.s[3] = f2bf(fmaxf(a0.w + b0.w, 0.f) + fmaxf(c0.w + d0.w, 0.f));
      float4 a1 = *(const float4*)(Ah + kb + 4);
      float4 c1 = *(const float4*)(Ch + kb + 4);
      float4 b1 = *(const float4*)(pB + kb + 4);
      float4 d1 = *(const float4*)(pD + kb + 4);
      u.s[4] = f2bf(fmaxf(a1.x + b1.x, 0.f) + fmaxf(c1.x + d1.x, 0.f));
      u.s[5] = f2bf(fmaxf(a1.y + b1.y, 0.f) + fmaxf(c1.y + d1.y, 0.f));
      u.s[6] = f2bf(fmaxf(a1.z + b1.z, 0.f) + fmaxf(c1.z + d1.z, 0.f));
      u.s[7] = f2bf(fmaxf(a1.w + b1.w, 0.f) + fmaxf(c1.w + d1.w, 0.f));
      *(uint4*)&smix[t * 8] = u.v;
    }
    // stage weight K-slice in frag order: slot s = pt*64 + (qq*16+cc)
    for (int s = t; s < 1216; s += 512){
      int pt = s >> 6, l = s & 63;
      int cc = l & 15, qq = l >> 4;
      uint4 w = *(const uint4*)(fc3bf + (pt*16 + cc)*KP + kc*32 + qq*8);
      *(uint4*)&swt[s * 8] = w;
    }
    __syncthreads();
    short8 af = *(const short8*)&smix[(wave*64 + lane) * 8];
    #pragma unroll
    for (int pt = 0; pt < 19; ++pt){
      short8 bf = *(const short8*)&swt[(pt*64 + lane) * 8];
      acc[pt] = __builtin_amdgcn_mfma_f32_16x16x32_bf16(af, bf, acc[pt], 0, 0, 0);
    }
    __syncthreads();
  }

  #pragma unroll
  for (int pt = 0; pt < 19; ++pt){
    int p = pt*16 + col;
    if (p < DD){
      float bias = fc3b[p];
      #pragma unroll
      for (int r = 0; r < 4; ++r){
        int m = mt0 + wave*16 + quad*4 + r;
        out[((size_t)n * NROW + m) * DD + p] = acc[pt][r] + bias;
      }
    }
  }
}

extern "C" void kernel_launch(void* const* d_in, const int* in_sizes, int n_in,
                              void* d_out, int out_size, void* d_ws, size_t ws_size,
                              hipStream_t stream) {
  const float* feature1 = (const float*)d_in[0];
  const float* box1     = (const float*)d_in[1];
  const float* feature2 = (const float*)d_in[2];
  const float* box2     = (const float*)d_in[3];
  const float* E        = (const float*)d_in[4];
  const float* gate1    = (const float*)d_in[5];
  const float* gate2    = (const float*)d_in[6];
  const float* wloc     = (const float*)d_in[7];
  const float* fc1w     = (const float*)d_in[8];
  const float* fc1b     = (const float*)d_in[9];
  const float* fc2w     = (const float*)d_in[10];
  const float* fc2b     = (const float*)d_in[11];
  const float* fc3w     = (const float*)d_in[12];
  const float* fc3b     = (const float*)d_in[13];
  float* out = (float*)d_out;
  float* ws  = (float*)d_ws;

  hipLaunchKernelGGL(k_prep, dim3(16), dim3(256), 0, stream, gate1, gate2, wloc, ws);
  hipLaunchKernelGGL(k_cvt_all, dim3((NX+NE+NF1+NF3)/256), dim3(256), 0, stream,
                     feature1, feature2, E, fc1w, fc3w, ws);
  hipLaunchKernelGGL(k_gg, dim3(120, 2), dim3(256), 0, stream, ws);
  hipLaunchKernelGGL(k_sem, dim3(120, 2), dim3(256), 0, stream, fc1b, ws);
  hipLaunchKernelGGL(k_spa, dim3(480, 2), dim3(256), 0, stream,
                     box1, box2, fc2w, fc2b, ws);
  hipLaunchKernelGGL(k_main, dim3(3, NROW), dim3(512), 0, stream, fc3b, out, ws);
}